// Round 6
// baseline (136.812 us; speedup 1.0000x reference)
//
#include <hip/hip_runtime.h>
#include <hip/hip_bf16.h>

#define C_DIM 512
#define L_DIM 1024
#define KK 64
#define KG 65
#define KP 80   // padded k rows (5 tiles of 16)

using f32x4  = __attribute__((ext_vector_type(4))) float;
using bf16x8 = __attribute__((ext_vector_type(8))) short;

union U4 { uint4 u; bf16x8 b; };

__device__ __forceinline__ unsigned bfh(float x) { return __float_as_uint(x) >> 16; }
__device__ __forceinline__ float bfh_f(float x) { return __uint_as_float(__float_as_uint(x) & 0xFFFF0000u); }

// pack two fp32 -> one u32 of their bf16 (truncated) halves: low16 = a, high16 = b
__device__ __forceinline__ unsigned pack2(float a, float b) {
    return __builtin_amdgcn_perm(__float_as_uint(b), __float_as_uint(a), 0x07060302u);
}
// from packed (hi|lo<<16) words p0,p1: extract the two hi16 (or lo16) into one u32
__device__ __forceinline__ unsigned hi2(unsigned p0, unsigned p1) {
    return __builtin_amdgcn_perm(p1, p0, 0x05040100u);
}
__device__ __forceinline__ unsigned lo2(unsigned p0, unsigned p1) {
    return __builtin_amdgcn_perm(p1, p0, 0x07060302u);
}

// ---------------- prep: split conv_w into bf16 hi/lo, pad to 80 rows ----------------
__global__ void k_prep(const float* __restrict__ conv_w, const float* __restrict__ conv_b,
                       unsigned short* __restrict__ wtH, unsigned short* __restrict__ wtL,
                       float* __restrict__ wb)
{
    int k = blockIdx.x;           // 0..79
    int t = threadIdx.x;          // 0..255, 2 c's each
    for (int j = 0; j < 2; ++j) {
        int c = t * 2 + j;
        float v = (k < KG) ? conv_w[k * C_DIM + c] : 0.f;
        unsigned h = bfh(v);
        float r = v - __uint_as_float(h << 16);
        wtH[k * C_DIM + c] = (unsigned short)h;
        wtL[k * C_DIM + c] = (unsigned short)bfh(r);
    }
    if (t == 0) wb[k] = (k < KG) ? conv_b[k] : -1e30f;
}

// ---------------- Stage 1: LDS-staged MFMA logits + softmax -> packed a' ----------------
// Grid (8 lb, 64 n), block 256 = 4 waves; wave owns 32 l (2 tiles of 16), all 5 k-tiles.
// Staging: thread reads 16 dwords (2x128B runs/instr), packs hi/lo bf16 in registers,
// writes contiguous uint2 rows to LDS [l][c] (pitch 40 shorts = 80B, b128-aligned).
__global__ __launch_bounds__(256) void k_s1(
    const float* __restrict__ x, const unsigned short* __restrict__ wtH,
    const unsigned short* __restrict__ wtL, const float* __restrict__ wb,
    unsigned* __restrict__ aPhl, float* __restrict__ asum_part)
{
    __shared__ unsigned short xh[128 * 40];
    __shared__ unsigned short xl[128 * 40];

    const int lb = blockIdx.x, n = blockIdx.y;
    const int t = threadIdx.x, lane = t & 63, w = t >> 6;
    const int lrel = lane & 31, half = lane >> 5;
    const int arow = lane & 15, agrp = lane >> 4;
    const int lloc0 = w * 32;            // wave-private 32-row LDS slice
    const int gl0 = lb * 128;            // block's global l base

    const float* xbase = x + (size_t)n * C_DIM * L_DIM;

    f32x4 acc[5][2];
#pragma unroll
    for (int a = 0; a < 5; ++a)
#pragma unroll
        for (int b = 0; b < 2; ++b) acc[a][b] = (f32x4)0.f;
    float ss = 0.f;

    for (int ch = 0; ch < 16; ++ch) {
        const int c0 = ch * 32;
        __syncthreads();
        // ---- read 16 c's at this thread's l (coalesced: 2x128B runs per instr)
        float xv[16];
#pragma unroll
        for (int j = 0; j < 16; ++j)
            xv[j] = xbase[(size_t)(c0 + half * 16 + j) * L_DIM + gl0 + lloc0 + lrel];
#pragma unroll
        for (int j = 0; j < 16; ++j) ss += xv[j] * xv[j];
        // ---- register transpose: pack and write contiguous uint2 (b64) rows
#pragma unroll
        for (int jg = 0; jg < 4; ++jg) {
            float a0 = xv[jg * 4], a1 = xv[jg * 4 + 1], a2 = xv[jg * 4 + 2], a3 = xv[jg * 4 + 3];
            uint2 hw, lw;
            hw.x = pack2(a0, a1); hw.y = pack2(a2, a3);
            float r0 = a0 - bfh_f(a0), r1 = a1 - bfh_f(a1);
            float r2 = a2 - bfh_f(a2), r3 = a3 - bfh_f(a3);
            lw.x = pack2(r0, r1); lw.y = pack2(r2, r3);
            int off = (lloc0 + lrel) * 40 + half * 16 + jg * 4;
            *reinterpret_cast<uint2*>(&xh[off]) = hw;
            *reinterpret_cast<uint2*>(&xl[off]) = lw;
        }
        __syncthreads();
        // ---- A fragments (weights, L1/L2-resident)
        U4 ah[5], al[5];
#pragma unroll
        for (int kt = 0; kt < 5; ++kt) {
            int aoff = (kt * 16 + arow) * C_DIM + c0 + agrp * 8;
            ah[kt].u = *reinterpret_cast<const uint4*>(&wtH[aoff]);
            al[kt].u = *reinterpret_cast<const uint4*>(&wtL[aoff]);
        }
        // ---- B fragments (LDS b128)
        U4 bh[2], bl[2];
#pragma unroll
        for (int lt = 0; lt < 2; ++lt) {
            int boff = (lloc0 + lt * 16 + arow) * 40 + agrp * 8;
            bh[lt].u = *reinterpret_cast<const uint4*>(&xh[boff]);
            bl[lt].u = *reinterpret_cast<const uint4*>(&xl[boff]);
        }
        // ---- 3-product split MFMA
#pragma unroll
        for (int kt = 0; kt < 5; ++kt)
#pragma unroll
            for (int lt = 0; lt < 2; ++lt) {
                acc[kt][lt] = __builtin_amdgcn_mfma_f32_16x16x32_bf16(ah[kt].b, bh[lt].b, acc[kt][lt], 0, 0, 0);
                acc[kt][lt] = __builtin_amdgcn_mfma_f32_16x16x32_bf16(ah[kt].b, bl[lt].b, acc[kt][lt], 0, 0, 0);
                acc[kt][lt] = __builtin_amdgcn_mfma_f32_16x16x32_bf16(al[kt].b, bh[lt].b, acc[kt][lt], 0, 0, 0);
            }
    }

    // ---- per-l inverse norm (lane & lane+32 hold the two c-halves of same l)
    ss += __shfl_xor(ss, 32, 64);
    const float inv = 1.0f / fmaxf(sqrtf(ss), 1e-12f);
    float invc[2];
    invc[0] = __shfl(inv, arow, 64);
    invc[1] = __shfl(inv, 16 + arow, 64);

    // ---- bias
    float4 wbv[5];
#pragma unroll
    for (int kt = 0; kt < 5; ++kt)
        wbv[kt] = *reinterpret_cast<const float4*>(&wb[kt * 16 + agrp * 4]);

    // ---- softmax per l (k spread over lanes {arow, arow+16, arow+32, arow+48})
    float aval[5][2][4];
    float rs[2];
#pragma unroll
    for (int lt = 0; lt < 2; ++lt) {
        float m = -1e30f;
#pragma unroll
        for (int kt = 0; kt < 5; ++kt)
#pragma unroll
            for (int r = 0; r < 4; ++r) {
                float lg = acc[kt][lt][r] * invc[lt] + ((const float*)&wbv[kt])[r];
                aval[kt][lt][r] = lg;
                m = fmaxf(m, lg);
            }
        m = fmaxf(m, __shfl_xor(m, 16, 64));
        m = fmaxf(m, __shfl_xor(m, 32, 64));
        float s = 0.f;
#pragma unroll
        for (int kt = 0; kt < 5; ++kt)
#pragma unroll
            for (int r = 0; r < 4; ++r) {
                float e = __expf(aval[kt][lt][r] - m);
                aval[kt][lt][r] = e;
                s += e;
            }
        s += __shfl_xor(s, 16, 64);
        s += __shfl_xor(s, 32, 64);
        rs[lt] = 1.0f / s;
    }

    // ---- a_sum partials + packed a' = a*inv (hi|lo<<16)
#pragma unroll
    for (int kt = 0; kt < 4; ++kt)
#pragma unroll
        for (int r = 0; r < 4; ++r) {
            int k = kt * 16 + agrp * 4 + r;
            float s01 = 0.f;
#pragma unroll
            for (int lt = 0; lt < 2; ++lt) {
                float a = aval[kt][lt][r] * rs[lt];
                aval[kt][lt][r] = a;
                s01 += a;
            }
#pragma unroll
            for (int off = 8; off; off >>= 1) s01 += __shfl_xor(s01, off, 64);
            if ((lane & 15) == 0)
                asum_part[((n * 8 + lb) * 4 + w) * KK + k] = s01;
#pragma unroll
            for (int lt = 0; lt < 2; ++lt) {
                float ap = aval[kt][lt][r] * invc[lt];
                unsigned h = bfh(ap);
                float res = ap - __uint_as_float(h << 16);
                aPhl[(size_t)(n * KK + k) * L_DIM + gl0 + lloc0 + lt * 16 + arow] =
                    h | (bfh(res) << 16);
            }
        }
}

// ---------------- Stage 2: weighted = a' x^T, LDS-staged MFMA GEMM ----------------
// Grid (8 cq, 64 n), block 256 = 4 waves; wave owns 16 c, all 4 k-tiles.
#define S2P 72   // LDS row pitch in shorts (144 B, 16B-aligned rows)
__global__ __launch_bounds__(256) void k_s2(
    const float* __restrict__ x, const unsigned* __restrict__ aPhl,
    float* __restrict__ weighted)
{
    __shared__ unsigned short Ah[64 * S2P], Al[64 * S2P];   // a' chunk [k][l]
    __shared__ unsigned short Bh[64 * S2P], Bl[64 * S2P];   // x  chunk [c][l]

    const int cq = blockIdx.x, n = blockIdx.y;
    const int t = threadIdx.x, lane = t & 63, w = t >> 6;
    const int arow = lane & 15, agrp = lane >> 4;

    f32x4 acc[4];
#pragma unroll
    for (int a = 0; a < 4; ++a) acc[a] = (f32x4)0.f;

    for (int step = 0; step < 16; ++step) {
        const int l0 = step * 64;
        __syncthreads();   // previous iter's reads done before restage
        // ---- stage a' [64k][64l]: packed u32 coalesced, unpack via v_perm
#pragma unroll
        for (int p = 0; p < 4; ++p) {
            int idx = p * 256 + t;          // 0..1023 uint4 (each = 4 packed l's)
            int k = idx >> 4;               // 16 uint4 per 64-word row
            int lc = (idx & 15) * 4;
            uint4 q = *reinterpret_cast<const uint4*>(
                &aPhl[(size_t)(n * KK + k) * L_DIM + l0 + lc]);
            uint2 hw, lw;
            hw.x = hi2(q.x, q.y); hw.y = hi2(q.z, q.w);
            lw.x = lo2(q.x, q.y); lw.y = lo2(q.z, q.w);
            *reinterpret_cast<uint2*>(&Ah[k * S2P + lc]) = hw;
            *reinterpret_cast<uint2*>(&Al[k * S2P + lc]) = lw;
        }
        // ---- stage x [64c][64l], split-convert to bf16 hi/lo at stage time
#pragma unroll
        for (int p = 0; p < 4; ++p) {
            int idx = p * 256 + t;          // 0..1023 (1024 float4)
            int c = idx >> 4;               // 16 float4 per 64-float row
            int lc = (idx & 15) * 4;
            float4 v = *reinterpret_cast<const float4*>(
                &x[((size_t)n * C_DIM + cq * 64 + c) * L_DIM + l0 + lc]);
            uint2 hw, lw;
            hw.x = pack2(v.x, v.y); hw.y = pack2(v.z, v.w);
            float r0 = v.x - bfh_f(v.x), r1 = v.y - bfh_f(v.y);
            float r2 = v.z - bfh_f(v.z), r3 = v.w - bfh_f(v.w);
            lw.x = pack2(r0, r1); lw.y = pack2(r2, r3);
            *reinterpret_cast<uint2*>(&Bh[c * S2P + lc]) = hw;
            *reinterpret_cast<uint2*>(&Bl[c * S2P + lc]) = lw;
        }
        __syncthreads();
        // ---- compute: 2 K=32 sub-steps
#pragma unroll
        for (int ks = 0; ks < 2; ++ks) {
            const int koff = ks * 32 + agrp * 8;
            U4 bh, bl;
            bh.u = *reinterpret_cast<const uint4*>(&Bh[(w * 16 + arow) * S2P + koff]);
            bl.u = *reinterpret_cast<const uint4*>(&Bl[(w * 16 + arow) * S2P + koff]);
#pragma unroll
            for (int kt = 0; kt < 4; ++kt) {
                U4 ah, al;
                ah.u = *reinterpret_cast<const uint4*>(&Ah[(kt * 16 + arow) * S2P + koff]);
                al.u = *reinterpret_cast<const uint4*>(&Al[(kt * 16 + arow) * S2P + koff]);
                acc[kt] = __builtin_amdgcn_mfma_f32_16x16x32_bf16(ah.b, bh.b, acc[kt], 0, 0, 0);
                acc[kt] = __builtin_amdgcn_mfma_f32_16x16x32_bf16(ah.b, bl.b, acc[kt], 0, 0, 0);
                acc[kt] = __builtin_amdgcn_mfma_f32_16x16x32_bf16(al.b, bh.b, acc[kt], 0, 0, 0);
            }
        }
    }
#pragma unroll
    for (int kt = 0; kt < 4; ++kt)
#pragma unroll
        for (int r = 0; r < 4; ++r) {
            int k = kt * 16 + agrp * 4 + r;
            weighted[((size_t)n * KK + k) * C_DIM + cq * 64 + w * 16 + arow] = acc[kt][r];
        }
}

// ---------------- per-(n,k): a_sum + row sumsq of vlad ----------------
__global__ void k_rownorm(const float* __restrict__ weighted, const float* __restrict__ part,
                          const float* __restrict__ cent, float* __restrict__ a_sum,
                          float* __restrict__ rn)
{
    int nk = blockIdx.x;          // 0..4095
    int n = nk >> 6, k = nk & 63;
    int t = threadIdx.x;          // 256
    float as = 0.f;
#pragma unroll
    for (int p = 0; p < 32; ++p) as += part[(n * 32 + p) * KK + k];
    if (t == 0) a_sum[nk] = as;
    float s = 0.f;
    for (int c = t; c < C_DIM; c += 256) {
        float v = weighted[(size_t)nk * C_DIM + c] - as * cent[k * C_DIM + c];
        s += v * v;
    }
#pragma unroll
    for (int off = 32; off; off >>= 1) s += __shfl_down(s, off, 64);
    __shared__ float red[4];
    if ((t & 63) == 0) red[t >> 6] = s;
    __syncthreads();
    if (t == 0) rn[nk] = red[0] + red[1] + red[2] + red[3];
}

// ---------------- per-n global norm -> combined scale ----------------
__global__ void k_scale(const float* __restrict__ rn, float* __restrict__ scale)
{
    int n = blockIdx.x;
    int k = threadIdx.x;    // 64
    float s = rn[n * 64 + k];
    float nrm = sqrtf(s);
    float den = fmaxf(nrm, 1e-12f);
    float tk = nrm / den;
    float tot = tk * tk;
#pragma unroll
    for (int off = 32; off; off >>= 1) tot += __shfl_down(tot, off, 64);
    tot = __shfl(tot, 0, 64);
    float g = fmaxf(sqrtf(tot), 1e-12f);
    scale[n * 64 + k] = 1.0f / (den * g);
}

// ---------------- final output ----------------
__global__ void k_out(const float* __restrict__ weighted, const float* __restrict__ a_sum,
                      const float* __restrict__ cent, const float* __restrict__ scale,
                      float* __restrict__ out)
{
    int nk = blockIdx.x;
    int k = nk & 63;
    int t = threadIdx.x;
    float as = a_sum[nk];
    float sc = scale[nk];
    for (int c = t; c < C_DIM; c += 256) {
        float v = weighted[(size_t)nk * C_DIM + c] - as * cent[k * C_DIM + c];
        out[(size_t)nk * C_DIM + c] = v * sc;
    }
}

extern "C" void kernel_launch(void* const* d_in, const int* in_sizes, int n_in,
                              void* d_out, int out_size, void* d_ws, size_t ws_size,
                              hipStream_t stream)
{
    const float* x    = (const float*)d_in[0];
    const float* cent = (const float*)d_in[1];
    const float* cw   = (const float*)d_in[2];
    const float* cb   = (const float*)d_in[3];
    float* out = (float*)d_out;
    char* ws = (char*)d_ws;

    unsigned short* wtH = (unsigned short*)(ws + 0);                // 80 KB
    unsigned short* wtL = (unsigned short*)(ws + 131072);           // 80 KB
    float*          wb  = (float*)(ws + 262144);                    // 320 B
    unsigned*       aPhl= (unsigned*)(ws + 524288);                 // 16 MB packed
    float* asum_part    = (float*)(ws + 17301504);                  // 512 KB
    float* a_sum        = (float*)(ws + 17825792);                  // 16 KB
    float* weighted     = (float*)(ws + 18874368);                  // 8 MB
    float* rn           = (float*)(ws + 35651584);
    float* scale        = (float*)(ws + 35667968);

    k_prep<<<KP, 256, 0, stream>>>(cw, cb, wtH, wtL, wb);
    k_s1<<<dim3(8, 64), 256, 0, stream>>>(x, wtH, wtL, wb, aPhl, asum_part);
    k_s2<<<dim3(8, 64), 256, 0, stream>>>(x, aPhl, weighted);
    k_rownorm<<<4096, 256, 0, stream>>>(weighted, asum_part, cent, a_sum, rn);
    k_scale<<<64, 64, 0, stream>>>(rn, scale);
    k_out<<<4096, 256, 0, stream>>>(weighted, a_sum, cent, scale, out);
}

// Round 7
// 131.226 us; speedup vs baseline: 1.0426x; 1.0426x over previous
//
#include <hip/hip_runtime.h>
#include <hip/hip_bf16.h>

#define C_DIM 512
#define L_DIM 1024
#define KK 64
#define KG 65
#define KP 80   // padded k rows (5 tiles of 16)

using f32x4  = __attribute__((ext_vector_type(4))) float;
using bf16x8 = __attribute__((ext_vector_type(8))) short;

union U4 { uint4 u; bf16x8 b; };

__device__ __forceinline__ unsigned bfh(float x) { return __float_as_uint(x) >> 16; }
__device__ __forceinline__ float bfh_f(float x) { return __uint_as_float(__float_as_uint(x) & 0xFFFF0000u); }

// pack two fp32 -> one u32 of their bf16 (truncated) halves: low16 = a, high16 = b
__device__ __forceinline__ unsigned pack2(float a, float b) {
    return __builtin_amdgcn_perm(__float_as_uint(b), __float_as_uint(a), 0x07060302u);
}
// from packed (hi|lo<<16) words p0,p1: extract the two hi16 (or lo16) into one u32
__device__ __forceinline__ unsigned hi2(unsigned p0, unsigned p1) {
    return __builtin_amdgcn_perm(p1, p0, 0x05040100u);
}
__device__ __forceinline__ unsigned lo2(unsigned p0, unsigned p1) {
    return __builtin_amdgcn_perm(p1, p0, 0x07060302u);
}

// ---------------- prep: split conv_w into bf16 hi/lo, pad to 80 rows ----------------
__global__ void k_prep(const float* __restrict__ conv_w, const float* __restrict__ conv_b,
                       unsigned short* __restrict__ wtH, unsigned short* __restrict__ wtL,
                       float* __restrict__ wb)
{
    int k = blockIdx.x;           // 0..79
    int t = threadIdx.x;          // 0..255, 2 c's each
    for (int j = 0; j < 2; ++j) {
        int c = t * 2 + j;
        float v = (k < KG) ? conv_w[k * C_DIM + c] : 0.f;
        unsigned h = bfh(v);
        float r = v - __uint_as_float(h << 16);
        wtH[k * C_DIM + c] = (unsigned short)h;
        wtL[k * C_DIM + c] = (unsigned short)bfh(r);
    }
    if (t == 0) wb[k] = (k < KG) ? conv_b[k] : -1e30f;
}

// ---------------- Stage 1: wave-private LDS staging, NO barriers ----------------
// Grid (8 lb, 64 n), block 256 = 4 waves; wave owns 32 l (2 tiles of 16), all 5 k-tiles.
// Each wave stages only its own 32-row LDS slice -> intra-wave lgkmcnt ordering
// suffices; cross-wave overlap hides global-load latency under MFMA.
__global__ __launch_bounds__(256) void k_s1(
    const float* __restrict__ x, const unsigned short* __restrict__ wtH,
    const unsigned short* __restrict__ wtL, const float* __restrict__ wb,
    unsigned* __restrict__ aPhl, float* __restrict__ asum_part)
{
    __shared__ unsigned short xh[128 * 40];
    __shared__ unsigned short xl[128 * 40];

    const int lb = blockIdx.x, n = blockIdx.y;
    const int t = threadIdx.x, lane = t & 63, w = t >> 6;
    const int lrel = lane & 31, half = lane >> 5;
    const int arow = lane & 15, agrp = lane >> 4;
    const int lloc0 = w * 32;            // wave-private 32-row LDS slice
    const int gl0 = lb * 128;            // block's global l base

    const float* xbase = x + (size_t)n * C_DIM * L_DIM;

    f32x4 acc[5][2];
#pragma unroll
    for (int a = 0; a < 5; ++a)
#pragma unroll
        for (int b = 0; b < 2; ++b) acc[a][b] = (f32x4)0.f;
    float ss = 0.f;

    for (int ch = 0; ch < 16; ++ch) {
        const int c0 = ch * 32;
        // ---- read 16 c's at this thread's l (coalesced: 2x128B runs per instr)
        float xv[16];
#pragma unroll
        for (int j = 0; j < 16; ++j)
            xv[j] = xbase[(size_t)(c0 + half * 16 + j) * L_DIM + gl0 + lloc0 + lrel];
#pragma unroll
        for (int j = 0; j < 16; ++j) ss += xv[j] * xv[j];
        // ---- register transpose: pack and write contiguous uint2 (b64) rows
#pragma unroll
        for (int jg = 0; jg < 4; ++jg) {
            float a0 = xv[jg * 4], a1 = xv[jg * 4 + 1], a2 = xv[jg * 4 + 2], a3 = xv[jg * 4 + 3];
            uint2 hw, lw;
            hw.x = pack2(a0, a1); hw.y = pack2(a2, a3);
            float r0 = a0 - bfh_f(a0), r1 = a1 - bfh_f(a1);
            float r2 = a2 - bfh_f(a2), r3 = a3 - bfh_f(a3);
            lw.x = pack2(r0, r1); lw.y = pack2(r2, r3);
            int off = (lloc0 + lrel) * 40 + half * 16 + jg * 4;
            *reinterpret_cast<uint2*>(&xh[off]) = hw;
            *reinterpret_cast<uint2*>(&xl[off]) = lw;
        }
        // ---- A fragments (weights, L1/L2-resident)
        U4 ah[5], al[5];
#pragma unroll
        for (int kt = 0; kt < 5; ++kt) {
            int aoff = (kt * 16 + arow) * C_DIM + c0 + agrp * 8;
            ah[kt].u = *reinterpret_cast<const uint4*>(&wtH[aoff]);
            al[kt].u = *reinterpret_cast<const uint4*>(&wtL[aoff]);
        }
        // ---- B fragments (wave-private LDS, b128)
        U4 bh[2], bl[2];
#pragma unroll
        for (int lt = 0; lt < 2; ++lt) {
            int boff = (lloc0 + lt * 16 + arow) * 40 + agrp * 8;
            bh[lt].u = *reinterpret_cast<const uint4*>(&xh[boff]);
            bl[lt].u = *reinterpret_cast<const uint4*>(&xl[boff]);
        }
        // ---- 3-product split MFMA
#pragma unroll
        for (int kt = 0; kt < 5; ++kt)
#pragma unroll
            for (int lt = 0; lt < 2; ++lt) {
                acc[kt][lt] = __builtin_amdgcn_mfma_f32_16x16x32_bf16(ah[kt].b, bh[lt].b, acc[kt][lt], 0, 0, 0);
                acc[kt][lt] = __builtin_amdgcn_mfma_f32_16x16x32_bf16(ah[kt].b, bl[lt].b, acc[kt][lt], 0, 0, 0);
                acc[kt][lt] = __builtin_amdgcn_mfma_f32_16x16x32_bf16(al[kt].b, bh[lt].b, acc[kt][lt], 0, 0, 0);
            }
    }

    // ---- per-l inverse norm (lane & lane+32 hold the two c-halves of same l)
    ss += __shfl_xor(ss, 32, 64);
    const float inv = 1.0f / fmaxf(sqrtf(ss), 1e-12f);
    float invc[2];
    invc[0] = __shfl(inv, arow, 64);
    invc[1] = __shfl(inv, 16 + arow, 64);

    // ---- bias
    float4 wbv[5];
#pragma unroll
    for (int kt = 0; kt < 5; ++kt)
        wbv[kt] = *reinterpret_cast<const float4*>(&wb[kt * 16 + agrp * 4]);

    // ---- softmax per l (k spread over lanes {arow, arow+16, arow+32, arow+48})
    float aval[5][2][4];
    float rs[2];
#pragma unroll
    for (int lt = 0; lt < 2; ++lt) {
        float m = -1e30f;
#pragma unroll
        for (int kt = 0; kt < 5; ++kt)
#pragma unroll
            for (int r = 0; r < 4; ++r) {
                float lg = acc[kt][lt][r] * invc[lt] + ((const float*)&wbv[kt])[r];
                aval[kt][lt][r] = lg;
                m = fmaxf(m, lg);
            }
        m = fmaxf(m, __shfl_xor(m, 16, 64));
        m = fmaxf(m, __shfl_xor(m, 32, 64));
        float s = 0.f;
#pragma unroll
        for (int kt = 0; kt < 5; ++kt)
#pragma unroll
            for (int r = 0; r < 4; ++r) {
                float e = __expf(aval[kt][lt][r] - m);
                aval[kt][lt][r] = e;
                s += e;
            }
        s += __shfl_xor(s, 16, 64);
        s += __shfl_xor(s, 32, 64);
        rs[lt] = 1.0f / s;
    }

    // ---- a_sum partials + packed a' = a*inv (hi|lo<<16)
#pragma unroll
    for (int kt = 0; kt < 4; ++kt)
#pragma unroll
        for (int r = 0; r < 4; ++r) {
            int k = kt * 16 + agrp * 4 + r;
            float s01 = 0.f;
#pragma unroll
            for (int lt = 0; lt < 2; ++lt) {
                float a = aval[kt][lt][r] * rs[lt];
                aval[kt][lt][r] = a;
                s01 += a;
            }
#pragma unroll
            for (int off = 8; off; off >>= 1) s01 += __shfl_xor(s01, off, 64);
            if ((lane & 15) == 0)
                asum_part[((n * 8 + lb) * 4 + w) * KK + k] = s01;
#pragma unroll
            for (int lt = 0; lt < 2; ++lt) {
                float ap = aval[kt][lt][r] * invc[lt];
                unsigned h = bfh(ap);
                float res = ap - __uint_as_float(h << 16);
                aPhl[(size_t)(n * KK + k) * L_DIM + gl0 + lloc0 + lt * 16 + arow] =
                    h | (bfh(res) << 16);
            }
        }
}

// ---------------- Stage 2: weighted = a' x^T, LDS-staged MFMA GEMM ----------------
// Grid (8 cq, 64 n), block 256 = 4 waves; wave owns 16 c, all 4 k-tiles.
#define S2P 72   // LDS row pitch in shorts (144 B, 16B-aligned rows)
__global__ __launch_bounds__(256) void k_s2(
    const float* __restrict__ x, const unsigned* __restrict__ aPhl,
    float* __restrict__ weighted)
{
    __shared__ unsigned short Ah[64 * S2P], Al[64 * S2P];   // a' chunk [k][l]
    __shared__ unsigned short Bh[64 * S2P], Bl[64 * S2P];   // x  chunk [c][l]

    const int cq = blockIdx.x, n = blockIdx.y;
    const int t = threadIdx.x, lane = t & 63, w = t >> 6;
    const int arow = lane & 15, agrp = lane >> 4;

    f32x4 acc[4];
#pragma unroll
    for (int a = 0; a < 4; ++a) acc[a] = (f32x4)0.f;

    for (int step = 0; step < 16; ++step) {
        const int l0 = step * 64;
        __syncthreads();   // previous iter's reads done before restage
        // ---- stage a' [64k][64l]: packed u32 coalesced, unpack via v_perm
#pragma unroll
        for (int p = 0; p < 4; ++p) {
            int idx = p * 256 + t;          // 0..1023 uint4 (each = 4 packed l's)
            int k = idx >> 4;               // 16 uint4 per 64-word row
            int lc = (idx & 15) * 4;
            uint4 q = *reinterpret_cast<const uint4*>(
                &aPhl[(size_t)(n * KK + k) * L_DIM + l0 + lc]);
            uint2 hw, lw;
            hw.x = hi2(q.x, q.y); hw.y = hi2(q.z, q.w);
            lw.x = lo2(q.x, q.y); lw.y = lo2(q.z, q.w);
            *reinterpret_cast<uint2*>(&Ah[k * S2P + lc]) = hw;
            *reinterpret_cast<uint2*>(&Al[k * S2P + lc]) = lw;
        }
        // ---- stage x [64c][64l], split-convert to bf16 hi/lo at stage time
#pragma unroll
        for (int p = 0; p < 4; ++p) {
            int idx = p * 256 + t;          // 0..1023 (1024 float4)
            int c = idx >> 4;               // 16 float4 per 64-float row
            int lc = (idx & 15) * 4;
            float4 v = *reinterpret_cast<const float4*>(
                &x[((size_t)n * C_DIM + cq * 64 + c) * L_DIM + l0 + lc]);
            uint2 hw, lw;
            hw.x = pack2(v.x, v.y); hw.y = pack2(v.z, v.w);
            float r0 = v.x - bfh_f(v.x), r1 = v.y - bfh_f(v.y);
            float r2 = v.z - bfh_f(v.z), r3 = v.w - bfh_f(v.w);
            lw.x = pack2(r0, r1); lw.y = pack2(r2, r3);
            *reinterpret_cast<uint2*>(&Bh[c * S2P + lc]) = hw;
            *reinterpret_cast<uint2*>(&Bl[c * S2P + lc]) = lw;
        }
        __syncthreads();
        // ---- compute: 2 K=32 sub-steps
#pragma unroll
        for (int ks = 0; ks < 2; ++ks) {
            const int koff = ks * 32 + agrp * 8;
            U4 bh, bl;
            bh.u = *reinterpret_cast<const uint4*>(&Bh[(w * 16 + arow) * S2P + koff]);
            bl.u = *reinterpret_cast<const uint4*>(&Bl[(w * 16 + arow) * S2P + koff]);
#pragma unroll
            for (int kt = 0; kt < 4; ++kt) {
                U4 ah, al;
                ah.u = *reinterpret_cast<const uint4*>(&Ah[(kt * 16 + arow) * S2P + koff]);
                al.u = *reinterpret_cast<const uint4*>(&Al[(kt * 16 + arow) * S2P + koff]);
                acc[kt] = __builtin_amdgcn_mfma_f32_16x16x32_bf16(ah.b, bh.b, acc[kt], 0, 0, 0);
                acc[kt] = __builtin_amdgcn_mfma_f32_16x16x32_bf16(ah.b, bl.b, acc[kt], 0, 0, 0);
                acc[kt] = __builtin_amdgcn_mfma_f32_16x16x32_bf16(al.b, bh.b, acc[kt], 0, 0, 0);
            }
        }
    }
#pragma unroll
    for (int kt = 0; kt < 4; ++kt)
#pragma unroll
        for (int r = 0; r < 4; ++r) {
            int k = kt * 16 + agrp * 4 + r;
            weighted[((size_t)n * KK + k) * C_DIM + cq * 64 + w * 16 + arow] = acc[kt][r];
        }
}

// ---------------- per-(n,k): a_sum + row sumsq of vlad ----------------
__global__ void k_rownorm(const float* __restrict__ weighted, const float* __restrict__ part,
                          const float* __restrict__ cent, float* __restrict__ a_sum,
                          float* __restrict__ rn)
{
    int nk = blockIdx.x;          // 0..4095
    int n = nk >> 6, k = nk & 63;
    int t = threadIdx.x;          // 256
    float as = 0.f;
#pragma unroll
    for (int p = 0; p < 32; ++p) as += part[(n * 32 + p) * KK + k];
    if (t == 0) a_sum[nk] = as;
    float s = 0.f;
    for (int c = t; c < C_DIM; c += 256) {
        float v = weighted[(size_t)nk * C_DIM + c] - as * cent[k * C_DIM + c];
        s += v * v;
    }
#pragma unroll
    for (int off = 32; off; off >>= 1) s += __shfl_down(s, off, 64);
    __shared__ float red[4];
    if ((t & 63) == 0) red[t >> 6] = s;
    __syncthreads();
    if (t == 0) rn[nk] = red[0] + red[1] + red[2] + red[3];
}

// ---------------- per-n global norm -> combined scale ----------------
__global__ void k_scale(const float* __restrict__ rn, float* __restrict__ scale)
{
    int n = blockIdx.x;
    int k = threadIdx.x;    // 64
    float s = rn[n * 64 + k];
    float nrm = sqrtf(s);
    float den = fmaxf(nrm, 1e-12f);
    float tk = nrm / den;
    float tot = tk * tk;
#pragma unroll
    for (int off = 32; off; off >>= 1) tot += __shfl_down(tot, off, 64);
    tot = __shfl(tot, 0, 64);
    float g = fmaxf(sqrtf(tot), 1e-12f);
    scale[n * 64 + k] = 1.0f / (den * g);
}

// ---------------- final output ----------------
__global__ void k_out(const float* __restrict__ weighted, const float* __restrict__ a_sum,
                      const float* __restrict__ cent, const float* __restrict__ scale,
                      float* __restrict__ out)
{
    int nk = blockIdx.x;
    int k = nk & 63;
    int t = threadIdx.x;
    float as = a_sum[nk];
    float sc = scale[nk];
    for (int c = t; c < C_DIM; c += 256) {
        float v = weighted[(size_t)nk * C_DIM + c] - as * cent[k * C_DIM + c];
        out[(size_t)nk * C_DIM + c] = v * sc;
    }
}

extern "C" void kernel_launch(void* const* d_in, const int* in_sizes, int n_in,
                              void* d_out, int out_size, void* d_ws, size_t ws_size,
                              hipStream_t stream)
{
    const float* x    = (const float*)d_in[0];
    const float* cent = (const float*)d_in[1];
    const float* cw   = (const float*)d_in[2];
    const float* cb   = (const float*)d_in[3];
    float* out = (float*)d_out;
    char* ws = (char*)d_ws;

    unsigned short* wtH = (unsigned short*)(ws + 0);                // 80 KB
    unsigned short* wtL = (unsigned short*)(ws + 131072);           // 80 KB
    float*          wb  = (float*)(ws + 262144);                    // 320 B
    unsigned*       aPhl= (unsigned*)(ws + 524288);                 // 16 MB packed
    float* asum_part    = (float*)(ws + 17301504);                  // 512 KB
    float* a_sum        = (float*)(ws + 17825792);                  // 16 KB
    float* weighted     = (float*)(ws + 18874368);                  // 8 MB
    float* rn           = (float*)(ws + 35651584);
    float* scale        = (float*)(ws + 35667968);

    k_prep<<<KP, 256, 0, stream>>>(cw, cb, wtH, wtL, wb);
    k_s1<<<dim3(8, 64), 256, 0, stream>>>(x, wtH, wtL, wb, aPhl, asum_part);
    k_s2<<<dim3(8, 64), 256, 0, stream>>>(x, aPhl, weighted);
    k_rownorm<<<4096, 256, 0, stream>>>(weighted, asum_part, cent, a_sum, rn);
    k_scale<<<64, 64, 0, stream>>>(rn, scale);
    k_out<<<4096, 256, 0, stream>>>(weighted, a_sum, cent, scale, out);
}